// Round 1
// baseline (6567.876 us; speedup 1.0000x reference)
//
#include <hip/hip_runtime.h>

#define N_NODES 50000
#define N_EDGES 800000
#define N_GRAPHS 256
#define N_LAYERS 3
#define DIM 300
#define NFEAT 128
#define EFEAT 16
#define OUTD 128
#define BN_EPS 1e-5f

// ---------------------------------------------------------------------------
// Tiled fp32 SGEMM with bias: C[M,Ncol] = A[M,K] @ B[K,Ncol] + bias[Ncol]
// 64x64 tile, BK=16, 256 threads, 4x4 micro-tile per thread.
// As stored transposed [k][m] with +4 pad (b128-aligned rows, <=2-way write
// conflicts which are free on gfx950); Bs [k][n] conflict-free.
// ---------------------------------------------------------------------------
#define TS 64
#define BK 16
#define ASP 68

__global__ __launch_bounds__(256) void sgemm_bias(
    const float* __restrict__ A, const float* __restrict__ B,
    const float* __restrict__ bias, float* __restrict__ C,
    int M, int Ncol, int K)
{
    __shared__ float As[BK][ASP];
    __shared__ float Bs[BK][TS];
    const int tid = threadIdx.x;
    const int bm = blockIdx.x * TS;
    const int bn = blockIdx.y * TS;
    const int tm = (tid >> 4) * 4;   // 0..60
    const int tn = (tid & 15) * 4;   // 0..60
    float acc[4][4] = {};

    for (int k0 = 0; k0 < K; k0 += BK) {
        // A tile: 64 rows x 16 k. consecutive tid -> consecutive k (coalesced 64B)
        #pragma unroll
        for (int i = 0; i < 4; ++i) {
            int idx = tid + i * 256;
            int m = idx >> 4;
            int k = idx & 15;
            int row = bm + m, kk = k0 + k;
            float v = 0.f;
            if (row < M && kk < K) v = A[(size_t)row * K + kk];
            As[k][m] = v;
        }
        // B tile: 16 k x 64 n. consecutive tid -> consecutive n (coalesced 256B)
        #pragma unroll
        for (int i = 0; i < 4; ++i) {
            int idx = tid + i * 256;
            int k = idx >> 6;
            int n = idx & 63;
            int col = bn + n, kk = k0 + k;
            float v = 0.f;
            if (col < Ncol && kk < K) v = B[(size_t)kk * Ncol + col];
            Bs[k][n] = v;
        }
        __syncthreads();
        #pragma unroll
        for (int k = 0; k < BK; ++k) {
            float4 av = *(const float4*)&As[k][tm];
            float4 bv = *(const float4*)&Bs[k][tn];
            float a4[4] = {av.x, av.y, av.z, av.w};
            float b4[4] = {bv.x, bv.y, bv.z, bv.w};
            #pragma unroll
            for (int i = 0; i < 4; ++i)
                #pragma unroll
                for (int j = 0; j < 4; ++j)
                    acc[i][j] = fmaf(a4[i], b4[j], acc[i][j]);
        }
        __syncthreads();
    }

    #pragma unroll
    for (int i = 0; i < 4; ++i) {
        int row = bm + tm + i;
        if (row >= M) continue;
        #pragma unroll
        for (int j = 0; j < 4; ++j) {
            int col = bn + tn + j;
            if (col < Ncol)
                C[(size_t)row * Ncol + col] = acc[i][j] + bias[col];
        }
    }
}

// ---------------------------------------------------------------------------
// Fused edge-encode + gather + ReLU + scatter-add.
// grid.y = d-chunk (5 chunks of 64 covering DIM=300). Each wave holds the
// 16x64 slice of edge_W for its chunk in registers; loops over its edges with
// wave-uniform scalar loads of src/dst/edge_feat.
// agg must be pre-initialized to hn (self term: h = hn + agg).
// ---------------------------------------------------------------------------
#define EDGES_PER_WAVE 128

__global__ __launch_bounds__(256) void edge_msg(
    const float* __restrict__ hn, const float* __restrict__ edge_feat,
    const int* __restrict__ src, const int* __restrict__ dst,
    const float* __restrict__ eW, const float* __restrict__ eb,
    float* __restrict__ agg)
{
    const int lane = threadIdx.x & 63;
    const int wid = __builtin_amdgcn_readfirstlane(threadIdx.x >> 6);
    const int d = blockIdx.y * 64 + lane;
    const bool dv = (d < DIM);

    float w[EFEAT];
    #pragma unroll
    for (int k = 0; k < EFEAT; ++k) w[k] = dv ? eW[k * DIM + d] : 0.f;
    const float ebd = dv ? eb[d] : 0.f;

    const long gwave = (long)blockIdx.x * 4 + wid;
    const long e0 = gwave * EDGES_PER_WAVE;

    for (int t = 0; t < EDGES_PER_WAVE; ++t) {
        long e = e0 + t;
        if (e >= N_EDGES) break;
        int s = src[e];
        int dd = dst[e];
        const float* efp = edge_feat + e * EFEAT;
        float he = ebd;
        #pragma unroll
        for (int k = 0; k < EFEAT; ++k) he = fmaf(efp[k], w[k], he);
        if (dv) {
            float m = hn[(size_t)s * DIM + d] + he;
            if (m > 0.f) atomicAdd(&agg[(size_t)dd * DIM + d], m);
        }
    }
}

// ---------------------------------------------------------------------------
// Column sums / sum-of-squares over N_NODES rows (C <= 768). stats[0..C)=sum,
// stats[C..2C)=sumsq; must be zeroed before launch.
// ---------------------------------------------------------------------------
#define ROWS_PER_BLOCK 128

__global__ __launch_bounds__(256) void colstats(
    const float* __restrict__ x, float* __restrict__ stats, int C)
{
    const int tid = threadIdx.x;
    const int r0 = blockIdx.x * ROWS_PER_BLOCK;
    const int r1 = min(r0 + ROWS_PER_BLOCK, N_NODES);
    float s0 = 0, s1 = 0, s2 = 0, q0 = 0, q1 = 0, q2 = 0;
    const int c0 = tid, c1 = tid + 256, c2 = tid + 512;
    for (int r = r0; r < r1; ++r) {
        const float* row = x + (size_t)r * C;
        if (c0 < C) { float v = row[c0]; s0 += v; q0 = fmaf(v, v, q0); }
        if (c1 < C) { float v = row[c1]; s1 += v; q1 = fmaf(v, v, q1); }
        if (c2 < C) { float v = row[c2]; s2 += v; q2 = fmaf(v, v, q2); }
    }
    if (c0 < C) { atomicAdd(&stats[c0], s0); atomicAdd(&stats[C + c0], q0); }
    if (c1 < C) { atomicAdd(&stats[c1], s1); atomicAdd(&stats[C + c1], q1); }
    if (c2 < C) { atomicAdd(&stats[c2], s2); atomicAdd(&stats[C + c2], q2); }
}

// ab[0..C) = g * rsqrt(var+eps);  ab[C..2C) = beta - mean * a
__global__ __launch_bounds__(256) void bn_finalize(
    const float* __restrict__ stats, const float* __restrict__ g,
    const float* __restrict__ beta, float* __restrict__ ab, int C)
{
    int c = blockIdx.x * 256 + threadIdx.x;
    if (c >= C) return;
    const float invN = 1.f / (float)N_NODES;
    float m = stats[c] * invN;
    float v = stats[C + c] * invN - m * m;
    float a = g[c] * rsqrtf(v + BN_EPS);
    ab[c] = a;
    ab[C + c] = beta[c] - m * a;
}

// y = (relu?) x*a[c] + b[c]   (float4; C divisible by 4)
__global__ __launch_bounds__(256) void bn_apply(
    const float* __restrict__ x, const float* __restrict__ ab,
    float* __restrict__ y, int total4, int C, int relu)
{
    int i = blockIdx.x * 256 + threadIdx.x;
    if (i >= total4) return;
    float4 v = ((const float4*)x)[i];
    int c = (i << 2) % C;
    const float* a = ab + c;
    const float* bb = ab + C + c;
    float4 r;
    r.x = fmaf(v.x, a[0], bb[0]);
    r.y = fmaf(v.y, a[1], bb[1]);
    r.z = fmaf(v.z, a[2], bb[2]);
    r.w = fmaf(v.w, a[3], bb[3]);
    if (relu) {
        r.x = fmaxf(r.x, 0.f); r.y = fmaxf(r.y, 0.f);
        r.z = fmaxf(r.z, 0.f); r.w = fmaxf(r.w, 0.f);
    }
    ((float4*)y)[i] = r;
}

// ---------------------------------------------------------------------------
// Mean pooling over graphs
// ---------------------------------------------------------------------------
__global__ __launch_bounds__(256) void pool_cnt(
    const int* __restrict__ gid, float* __restrict__ cnt)
{
    int i = blockIdx.x * 256 + threadIdx.x;
    if (i < N_NODES) atomicAdd(&cnt[gid[i]], 1.f);
}

__global__ __launch_bounds__(256) void pool_scatter(
    const float* __restrict__ hn, const int* __restrict__ gid,
    float* __restrict__ hg)
{
    int idx = blockIdx.x * 256 + threadIdx.x;
    if (idx >= N_NODES * DIM) return;
    int node = idx / DIM;
    int d = idx - node * DIM;
    atomicAdd(&hg[gid[node] * DIM + d], hn[idx]);
}

__global__ __launch_bounds__(256) void pool_div(
    float* __restrict__ hg, const float* __restrict__ cnt)
{
    int i = blockIdx.x * 256 + threadIdx.x;
    if (i >= N_GRAPHS * DIM) return;
    int g = i / DIM;
    hg[i] /= fmaxf(cnt[g], 1.f);
}

// ---------------------------------------------------------------------------
extern "C" void kernel_launch(void* const* d_in, const int* in_sizes, int n_in,
                              void* d_out, int out_size, void* d_ws, size_t ws_size,
                              hipStream_t stream)
{
    const float* node_feat = (const float*)d_in[0];
    const float* edge_feat = (const float*)d_in[1];
    const int*   src       = (const int*)d_in[2];
    const int*   dst       = (const int*)d_in[3];
    const int*   gid       = (const int*)d_in[4];
    // d_in[5] = num_graphs (constant 256)
    const float* node_W = (const float*)d_in[6];
    const float* node_b = (const float*)d_in[7];
    const float* edge_W = (const float*)d_in[8];
    const float* edge_b = (const float*)d_in[9];
    const float* W1  = (const float*)d_in[10];
    const float* b1  = (const float*)d_in[11];
    const float* g1  = (const float*)d_in[12];
    const float* be1 = (const float*)d_in[13];
    const float* W2  = (const float*)d_in[14];
    const float* b2  = (const float*)d_in[15];
    const float* g2  = (const float*)d_in[16];
    const float* be2 = (const float*)d_in[17];
    const float* pred_W = (const float*)d_in[18];
    const float* pred_b = (const float*)d_in[19];
    float* out = (float*)d_out;

    // workspace layout (floats): hn | agg | x1 | stats(1200) | ab(1200) | hg | cnt
    float* hn    = (float*)d_ws;
    float* agg   = hn + (size_t)N_NODES * DIM;
    float* x1    = agg + (size_t)N_NODES * DIM;
    float* stats = x1 + (size_t)N_NODES * 2 * DIM;
    float* ab    = stats + 4 * DIM;
    float* hg    = ab + 4 * DIM;
    float* cnt   = hg + (size_t)N_GRAPHS * DIM;

    dim3 blk(256);

    // hn = node_feat @ node_W + node_b
    sgemm_bias<<<dim3((N_NODES + 63) / 64, (DIM + 63) / 64), blk, 0, stream>>>(
        node_feat, node_W, node_b, hn, N_NODES, DIM, NFEAT);

    const int egrid_x = (N_EDGES + 4 * EDGES_PER_WAVE - 1) / (4 * EDGES_PER_WAVE);

    for (int l = 0; l < N_LAYERS; ++l) {
        // agg = hn  (self term), then scatter messages on top
        hipMemcpyAsync(agg, hn, (size_t)N_NODES * DIM * sizeof(float),
                       hipMemcpyDeviceToDevice, stream);
        edge_msg<<<dim3(egrid_x, 5), blk, 0, stream>>>(
            hn, edge_feat, src, dst,
            edge_W + (size_t)l * EFEAT * DIM, edge_b + (size_t)l * DIM, agg);

        // x1 = h @ W1 + b1   [N, 600]
        sgemm_bias<<<dim3((N_NODES + 63) / 64, (2 * DIM + 63) / 64), blk, 0, stream>>>(
            agg, W1 + (size_t)l * DIM * 2 * DIM, b1 + (size_t)l * 2 * DIM, x1,
            N_NODES, 2 * DIM, DIM);
        // BN1 + relu (in place)
        hipMemsetAsync(stats, 0, 4 * DIM * sizeof(float), stream);
        colstats<<<dim3((N_NODES + ROWS_PER_BLOCK - 1) / ROWS_PER_BLOCK), blk, 0, stream>>>(
            x1, stats, 2 * DIM);
        bn_finalize<<<dim3((2 * DIM + 255) / 256), blk, 0, stream>>>(
            stats, g1 + (size_t)l * 2 * DIM, be1 + (size_t)l * 2 * DIM, ab, 2 * DIM);
        bn_apply<<<dim3((N_NODES * 2 * DIM / 4 + 255) / 256), blk, 0, stream>>>(
            x1, ab, x1, N_NODES * 2 * DIM / 4, 2 * DIM, 1);

        // x2 = x1 @ W2 + b2  [N, 300]  (into agg buffer)
        sgemm_bias<<<dim3((N_NODES + 63) / 64, (DIM + 63) / 64), blk, 0, stream>>>(
            x1, W2 + (size_t)l * 2 * DIM * DIM, b2 + (size_t)l * DIM, agg,
            N_NODES, DIM, 2 * DIM);
        // BN2 (+relu except last layer), write into hn for next layer
        hipMemsetAsync(stats, 0, 2 * DIM * sizeof(float), stream);
        colstats<<<dim3((N_NODES + ROWS_PER_BLOCK - 1) / ROWS_PER_BLOCK), blk, 0, stream>>>(
            agg, stats, DIM);
        bn_finalize<<<dim3((DIM + 255) / 256), blk, 0, stream>>>(
            stats, g2 + (size_t)l * DIM, be2 + (size_t)l * DIM, ab, DIM);
        bn_apply<<<dim3((N_NODES * DIM / 4 + 255) / 256), blk, 0, stream>>>(
            agg, ab, hn, N_NODES * DIM / 4, DIM, (l < N_LAYERS - 1) ? 1 : 0);
    }

    // mean pool per graph + prediction head
    hipMemsetAsync(hg, 0, ((size_t)N_GRAPHS * DIM + N_GRAPHS) * sizeof(float), stream);
    pool_cnt<<<dim3((N_NODES + 255) / 256), blk, 0, stream>>>(gid, cnt);
    pool_scatter<<<dim3((N_NODES * DIM + 255) / 256), blk, 0, stream>>>(hn, gid, hg);
    pool_div<<<dim3((N_GRAPHS * DIM + 255) / 256), blk, 0, stream>>>(hg, cnt);

    sgemm_bias<<<dim3((N_GRAPHS + 63) / 64, (OUTD + 63) / 64), blk, 0, stream>>>(
        hg, pred_W, pred_b, out, N_GRAPHS, OUTD, DIM);
}

// Round 3
// 3059.534 us; speedup vs baseline: 2.1467x; 2.1467x over previous
//
#include <hip/hip_runtime.h>

#define N_NODES 50000
#define N_EDGES 800000
#define N_GRAPHS 256
#define N_LAYERS 3
#define DIM 300
#define NFEAT 128
#define EFEAT 16
#define OUTD 128
#define BN_EPS 1e-5f

typedef __attribute__((ext_vector_type(8))) short bfrag8;   // 8 bf16 = 4 VGPR (MFMA A/B operand)
typedef __attribute__((ext_vector_type(4))) float facc4;    // MFMA C/D
typedef __attribute__((ext_vector_type(4))) unsigned short us4;

// ---------------- bf16 helpers (RNE) + hi/lo split ----------------
__device__ __forceinline__ unsigned short f2bf(float f) {
    unsigned u = __float_as_uint(f);
    unsigned r = ((u >> 16) & 1u) + 0x7fffu;
    return (unsigned short)((u + r) >> 16);
}
__device__ __forceinline__ float bf2f(unsigned short h) {
    return __uint_as_float(((unsigned)h) << 16);
}
__device__ __forceinline__ void split2(float v, unsigned short& h, unsigned short& l) {
    h = f2bf(v);
    l = f2bf(v - bf2f(h));
}
// float4 -> hi/lo us4 (vector elements cannot bind to refs; use scalar temps)
__device__ __forceinline__ void split2v(float4 v, us4& h, us4& l) {
    unsigned short a, b;
    split2(v.x, a, b); h.x = a; l.x = b;
    split2(v.y, a, b); h.y = a; l.y = b;
    split2(v.z, a, b); h.z = a; l.z = b;
    split2(v.w, a, b); h.w = a; l.w = b;
}

// async global->LDS, 16B per lane. LDS dest = uniform base + lane*16 (HW rule).
__device__ __forceinline__ void load_lds16(const void* gsrc, void* ldsdst) {
    __builtin_amdgcn_global_load_lds(
        (const __attribute__((address_space(1))) unsigned int*)gsrc,
        (__attribute__((address_space(3))) unsigned int*)ldsdst,
        16, 0, 0);
}

#define MFMA16(a, b, c) __builtin_amdgcn_mfma_f32_16x16x32_bf16(a, b, c, 0, 0, 0)

// ---------------------------------------------------------------------------
// split fp32 -> bf16 hi/lo planes (vectorized, n4 float4s)
// ---------------------------------------------------------------------------
__global__ __launch_bounds__(256) void split4(
    const float* __restrict__ x, unsigned short* __restrict__ H,
    unsigned short* __restrict__ L, int n4)
{
    int i = blockIdx.x * 256 + threadIdx.x;
    if (i >= n4) return;
    float4 v = ((const float4*)x)[i];
    us4 h, l;
    split2v(v, h, l);
    ((us4*)H)[i] = h;
    ((us4*)L)[i] = l;
}

// ---------------------------------------------------------------------------
// weight conversion: W fp32 [K][N] -> transposed padded planes [Np][Kp] bf16
// ---------------------------------------------------------------------------
__global__ __launch_bounds__(256) void conv_wt(
    const float* __restrict__ W, unsigned short* __restrict__ H,
    unsigned short* __restrict__ L, int K, int N, int Kp, int Np)
{
    int idx = blockIdx.x * 256 + threadIdx.x;
    if (idx >= Np * Kp) return;
    int n = idx / Kp;
    int k = idx - n * Kp;
    float v = (n < N && k < K) ? W[(size_t)k * N + n] : 0.f;
    unsigned short h, l;
    split2(v, h, l);
    H[idx] = h;
    L[idx] = l;
}

// ---------------------------------------------------------------------------
// Split-bf16 MFMA GEMM, A from pre-split planes.
// A: [M][Kp] bf16 hi/lo. Bt: [Np][Kp] bf16 hi/lo (B transposed, zero-padded).
// C = A@B + bias, fp32 [M][N] compact. Block 128x128, BK=32, 4 waves (2x2),
// wave tile 64x64 = 4x4 MFMA 16x16x32 tiles, 3 MFMA per tile (hh, hl, lh).
// ---------------------------------------------------------------------------
__global__ __launch_bounds__(256, 2) void gemm_pp(
    const unsigned short* __restrict__ Ah, const unsigned short* __restrict__ Al,
    const unsigned short* __restrict__ Bth, const unsigned short* __restrict__ Btl,
    const float* __restrict__ bias, float* __restrict__ C,
    int M, int N, int Kp)
{
    __shared__ unsigned short lds[16384];   // 32 KB: Ah|Al|Bh|Bl, 8KB each
    const int tid = threadIdx.x;
    const int lane = tid & 63;
    const int w = tid >> 6;
    const int m0 = blockIdx.x * 128;
    const int n0 = blockIdx.y * 128;
    const int wm = (w & 1) * 64;
    const int wn = (w >> 1) * 64;

    const int srow = lane >> 2;          // staging row within 16-row chunk
    const int scol = (lane & 3) * 8;     // staging 16B quad (8 bf16)

    // per-wave 8 staging chunk base pointers (k0 = 0)
    const unsigned short* gp[8];
    unsigned loff[8];
#pragma unroll
    for (int i = 0; i < 8; ++i) {
        int c = w * 8 + i;
        const unsigned short* pl = (c < 8) ? Ah : (c < 16) ? Al : (c < 24) ? Bth : Btl;
        int rowg;
        if (c < 16) {
            rowg = m0 + (c & 7) * 16 + srow;
            rowg = min(rowg, M - 1);
        } else {
            rowg = n0 + (c & 7) * 16 + srow;
        }
        gp[i] = pl + (size_t)rowg * Kp + scol;
        loff[i] = c * 512;               // ushort offset, 1KB chunks
    }

    facc4 acc[4][4];
    facc4 zero = {0.f, 0.f, 0.f, 0.f};
#pragma unroll
    for (int i = 0; i < 4; ++i)
#pragma unroll
        for (int j = 0; j < 4; ++j) acc[i][j] = zero;

    const int fr = lane & 15;
    const int fq = (lane >> 4) * 8;

    for (int k0 = 0; k0 < Kp; k0 += 32) {
#pragma unroll
        for (int i = 0; i < 8; ++i) {
            load_lds16(gp[i], &lds[loff[i]]);
            gp[i] += 32;
        }
        __syncthreads();

        bfrag8 ah[4], al[4], bh[4], bl[4];
#pragma unroll
        for (int t = 0; t < 4; ++t) {
            int ar = wm + t * 16 + fr;
            ah[t] = *(const bfrag8*)&lds[ar * 32 + fq];
            al[t] = *(const bfrag8*)&lds[4096 + ar * 32 + fq];
            int br = wn + t * 16 + fr;
            bh[t] = *(const bfrag8*)&lds[8192 + br * 32 + fq];
            bl[t] = *(const bfrag8*)&lds[12288 + br * 32 + fq];
        }
#pragma unroll
        for (int i = 0; i < 4; ++i)
#pragma unroll
            for (int j = 0; j < 4; ++j) {
                acc[i][j] = MFMA16(ah[i], bh[j], acc[i][j]);
                acc[i][j] = MFMA16(ah[i], bl[j], acc[i][j]);
                acc[i][j] = MFMA16(al[i], bh[j], acc[i][j]);
            }
        __syncthreads();
    }

    // epilogue: C/D layout col=lane&15, row=(lane>>4)*4+reg
#pragma unroll
    for (int i = 0; i < 4; ++i)
#pragma unroll
        for (int j = 0; j < 4; ++j) {
            int col = n0 + wn + j * 16 + (lane & 15);
            if (col >= N) continue;
            float bv = bias[col];
#pragma unroll
            for (int r = 0; r < 4; ++r) {
                int row = m0 + wm + i * 16 + (lane >> 4) * 4 + r;
                if (row < M)
                    C[(size_t)row * N + col] = acc[i][j][r] + bv;
            }
        }
}

// ---------------------------------------------------------------------------
// Split-bf16 MFMA GEMM, A fp32 converted to hi/lo during LDS staging.
// A: [M][K] fp32. Bt planes as above. Same tiling as gemm_pp.
// ---------------------------------------------------------------------------
__global__ __launch_bounds__(256, 2) void gemm_af(
    const float* __restrict__ A, const unsigned short* __restrict__ Bth,
    const unsigned short* __restrict__ Btl, const float* __restrict__ bias,
    float* __restrict__ C, int M, int N, int K, int Kp)
{
    __shared__ unsigned short lds[16384];
    const int tid = threadIdx.x;
    const int lane = tid & 63;
    const int w = tid >> 6;
    const int m0 = blockIdx.x * 128;
    const int n0 = blockIdx.y * 128;
    const int wm = (w & 1) * 64;
    const int wn = (w >> 1) * 64;

    const int srow = lane >> 2;
    const int scol = (lane & 3) * 8;

    // B staging: 16 chunks over 4 waves
    const unsigned short* gpb[4];
    unsigned loffb[4];
#pragma unroll
    for (int i = 0; i < 4; ++i) {
        int c = w * 4 + i;
        const unsigned short* pl = (c < 8) ? Bth : Btl;
        int rowg = n0 + (c & 7) * 16 + srow;
        gpb[i] = pl + (size_t)rowg * Kp + scol;
        loffb[i] = 8192 + c * 512;
    }

    facc4 acc[4][4];
    facc4 zero = {0.f, 0.f, 0.f, 0.f};
#pragma unroll
    for (int i = 0; i < 4; ++i)
#pragma unroll
        for (int j = 0; j < 4; ++j) acc[i][j] = zero;

    const int fr = lane & 15;
    const int fq = (lane >> 4) * 8;

    for (int k0 = 0; k0 < Kp; k0 += 32) {
#pragma unroll
        for (int i = 0; i < 4; ++i) {
            load_lds16(gpb[i], &lds[loffb[i]]);
            gpb[i] += 32;
        }
        // A fp32 -> split bf16 into LDS (128 rows x 32 k)
#pragma unroll
        for (int i = 0; i < 4; ++i) {
            int idx = tid + i * 256;
            int row = idx >> 3;
            int q4 = idx & 7;
            int rg = min(m0 + row, M - 1);
            int kk = k0 + q4 * 4;
            float4 v;
            if (kk < K) v = *(const float4*)&A[(size_t)rg * K + kk];
            else { v.x = 0.f; v.y = 0.f; v.z = 0.f; v.w = 0.f; }
            us4 h, l;
            split2v(v, h, l);
            *(us4*)&lds[row * 32 + q4 * 4] = h;
            *(us4*)&lds[4096 + row * 32 + q4 * 4] = l;
        }
        __syncthreads();

        bfrag8 ah[4], al[4], bh[4], bl[4];
#pragma unroll
        for (int t = 0; t < 4; ++t) {
            int ar = wm + t * 16 + fr;
            ah[t] = *(const bfrag8*)&lds[ar * 32 + fq];
            al[t] = *(const bfrag8*)&lds[4096 + ar * 32 + fq];
            int br = wn + t * 16 + fr;
            bh[t] = *(const bfrag8*)&lds[8192 + br * 32 + fq];
            bl[t] = *(const bfrag8*)&lds[12288 + br * 32 + fq];
        }
#pragma unroll
        for (int i = 0; i < 4; ++i)
#pragma unroll
            for (int j = 0; j < 4; ++j) {
                acc[i][j] = MFMA16(ah[i], bh[j], acc[i][j]);
                acc[i][j] = MFMA16(ah[i], bl[j], acc[i][j]);
                acc[i][j] = MFMA16(al[i], bh[j], acc[i][j]);
            }
        __syncthreads();
    }

#pragma unroll
    for (int i = 0; i < 4; ++i)
#pragma unroll
        for (int j = 0; j < 4; ++j) {
            int col = n0 + wn + j * 16 + (lane & 15);
            if (col >= N) continue;
            float bv = bias[col];
#pragma unroll
            for (int r = 0; r < 4; ++r) {
                int row = m0 + wm + i * 16 + (lane >> 4) * 4 + r;
                if (row < M)
                    C[(size_t)row * N + col] = acc[i][j][r] + bv;
            }
        }
}

// ---------------------------------------------------------------------------
// CSR build (dst-sorted). P has 50001 ints. counts at P[v+1]; after scan
// P[v] = start_v; after fill P[v] = end_v (gather uses P[v-1]..P[v]).
// ---------------------------------------------------------------------------
__global__ __launch_bounds__(256) void csr_count(const int* __restrict__ dst, int* __restrict__ P)
{
    int e = blockIdx.x * 256 + threadIdx.x;
    if (e < N_EDGES) atomicAdd(&P[dst[e] + 1], 1);
}

__global__ __launch_bounds__(1024) void csr_scan(int* __restrict__ P)
{
    __shared__ int part[1024];
    const int t = threadIdx.x;
    const int CH = 49;                       // 1024*49 = 50176 >= 50001
    int i0 = t * CH;
    int s = 0;
    for (int i = i0; i < i0 + CH; ++i) {
        if (i <= N_NODES) { s += P[i]; P[i] = s; }
    }
    part[t] = s;
    __syncthreads();
    if (t == 0) {
        int run = 0;
        for (int k = 0; k < 1024; ++k) { int tmp = part[k]; part[k] = run; run += tmp; }
    }
    __syncthreads();
    int off = part[t];
    for (int i = i0; i < i0 + CH; ++i) {
        if (i <= N_NODES) P[i] += off;
    }
}

__global__ __launch_bounds__(256) void csr_fill(
    const int* __restrict__ dst, int* __restrict__ P, int* __restrict__ eids)
{
    int e = blockIdx.x * 256 + threadIdx.x;
    if (e < N_EDGES) {
        int pos = atomicAdd(&P[dst[e]], 1);
        eids[pos] = e;
    }
}

// ---------------------------------------------------------------------------
// Gather aggregation: one wave per node. agg = hn[v] + sum_in relu(hn[src]+he)
// he = edge_feat[e] @ eW + eb, eW 16x300 slice held in registers (16x5 chunks).
// Output: split bf16 planes [N_NODES][320] (K-pad zeroed for GEMM1).
// ---------------------------------------------------------------------------
__global__ __launch_bounds__(256) void gather_agg(
    const float* __restrict__ hn, const float* __restrict__ edge_feat,
    const int* __restrict__ src, const int* __restrict__ eids,
    const int* __restrict__ P, const float* __restrict__ eW,
    const float* __restrict__ eb,
    unsigned short* __restrict__ aggH, unsigned short* __restrict__ aggL)
{
    const int v = blockIdx.x * 4 + (threadIdx.x >> 6);
    if (v >= N_NODES) return;
    const int lane = threadIdx.x & 63;

    float wr[EFEAT][5];
    float acc[5];
    float ebv[5];
#pragma unroll
    for (int c = 0; c < 5; ++c) {
        int d = lane + 64 * c;
        bool dv = d < DIM;
        acc[c] = dv ? hn[(size_t)v * DIM + d] : 0.f;
        ebv[c] = dv ? eb[d] : 0.f;
#pragma unroll
        for (int k = 0; k < EFEAT; ++k)
            wr[k][c] = dv ? eW[k * DIM + d] : 0.f;
    }

    const int j0 = (v == 0) ? 0 : P[v - 1];
    const int j1 = P[v];

    for (int j = j0; j < j1; ++j) {
        int e = __builtin_amdgcn_readfirstlane(eids[j]);
        int s = __builtin_amdgcn_readfirstlane(src[e]);
        const float* efp = edge_feat + (size_t)e * EFEAT;
        float ef[EFEAT];
#pragma unroll
        for (int k = 0; k < EFEAT; ++k) ef[k] = efp[k];
        const float* hp = hn + (size_t)s * DIM;
#pragma unroll
        for (int c = 0; c < 5; ++c) {
            int d = lane + 64 * c;
            float hv = (d < DIM) ? hp[d] : 0.f;
            float he = ebv[c];
#pragma unroll
            for (int k = 0; k < EFEAT; ++k) he = fmaf(ef[k], wr[k][c], he);
            float m = hv + he;
            acc[c] += fmaxf(m, 0.f);
        }
    }

#pragma unroll
    for (int c = 0; c < 5; ++c) {
        unsigned short h, l;
        split2(acc[c], h, l);
        size_t o = (size_t)v * 320 + lane + 64 * c;
        aggH[o] = h;
        aggL[o] = l;
    }
}

// ---------------------------------------------------------------------------
// BN: column stats -> finalize -> apply
// ---------------------------------------------------------------------------
#define ROWS_PER_BLOCK 128

__global__ __launch_bounds__(256) void colstats(
    const float* __restrict__ x, float* __restrict__ stats, int C)
{
    const int tid = threadIdx.x;
    const int r0 = blockIdx.x * ROWS_PER_BLOCK;
    const int r1 = min(r0 + ROWS_PER_BLOCK, N_NODES);
    float s0 = 0, s1 = 0, s2 = 0, q0 = 0, q1 = 0, q2 = 0;
    const int c0 = tid, c1 = tid + 256, c2 = tid + 512;
    for (int r = r0; r < r1; ++r) {
        const float* row = x + (size_t)r * C;
        if (c0 < C) { float v = row[c0]; s0 += v; q0 = fmaf(v, v, q0); }
        if (c1 < C) { float v = row[c1]; s1 += v; q1 = fmaf(v, v, q1); }
        if (c2 < C) { float v = row[c2]; s2 += v; q2 = fmaf(v, v, q2); }
    }
    if (c0 < C) { atomicAdd(&stats[c0], s0); atomicAdd(&stats[C + c0], q0); }
    if (c1 < C) { atomicAdd(&stats[c1], s1); atomicAdd(&stats[C + c1], q1); }
    if (c2 < C) { atomicAdd(&stats[c2], s2); atomicAdd(&stats[C + c2], q2); }
}

__global__ __launch_bounds__(256) void bn_finalize(
    const float* __restrict__ stats, const float* __restrict__ g,
    const float* __restrict__ beta, float* __restrict__ ab, int C)
{
    int c = blockIdx.x * 256 + threadIdx.x;
    if (c >= C) return;
    const float invN = 1.f / (float)N_NODES;
    float m = stats[c] * invN;
    float v = stats[C + c] * invN - m * m;
    float a = g[c] * rsqrtf(v + BN_EPS);
    ab[c] = a;
    ab[C + c] = beta[c] - m * a;
}

__global__ __launch_bounds__(256) void bn_apply(
    const float* __restrict__ x, const float* __restrict__ ab,
    float* __restrict__ y, int total4, int C, int relu)
{
    int i = blockIdx.x * 256 + threadIdx.x;
    if (i >= total4) return;
    float4 v = ((const float4*)x)[i];
    int c = (i << 2) % C;
    const float* a = ab + c;
    const float* bb = ab + C + c;
    float4 r;
    r.x = fmaf(v.x, a[0], bb[0]);
    r.y = fmaf(v.y, a[1], bb[1]);
    r.z = fmaf(v.z, a[2], bb[2]);
    r.w = fmaf(v.w, a[3], bb[3]);
    if (relu) {
        r.x = fmaxf(r.x, 0.f); r.y = fmaxf(r.y, 0.f);
        r.z = fmaxf(r.z, 0.f); r.w = fmaxf(r.w, 0.f);
    }
    ((float4*)y)[i] = r;
}

// ---------------------------------------------------------------------------
// Mean pooling + head
// ---------------------------------------------------------------------------
__global__ __launch_bounds__(256) void pool_cnt(
    const int* __restrict__ gid, float* __restrict__ cnt)
{
    int i = blockIdx.x * 256 + threadIdx.x;
    if (i < N_NODES) atomicAdd(&cnt[gid[i]], 1.f);
}

__global__ __launch_bounds__(256) void pool_scatter(
    const float* __restrict__ hn, const int* __restrict__ gid,
    float* __restrict__ hg)
{
    int idx = blockIdx.x * 256 + threadIdx.x;
    if (idx >= N_NODES * DIM) return;
    int node = idx / DIM;
    int d = idx - node * DIM;
    atomicAdd(&hg[gid[node] * DIM + d], hn[idx]);
}

__global__ __launch_bounds__(256) void pool_div(
    float* __restrict__ hg, const float* __restrict__ cnt)
{
    int i = blockIdx.x * 256 + threadIdx.x;
    if (i >= N_GRAPHS * DIM) return;
    int g = i / DIM;
    hg[i] /= fmaxf(cnt[g], 1.f);
}

// fp32 tiled sgemm for the tiny prediction head
#define TS 64
#define BK 16
#define ASP 68

__global__ __launch_bounds__(256) void sgemm_bias(
    const float* __restrict__ A, const float* __restrict__ B,
    const float* __restrict__ bias, float* __restrict__ C,
    int M, int Ncol, int K)
{
    __shared__ float As[BK][ASP];
    __shared__ float Bs[BK][TS];
    const int tid = threadIdx.x;
    const int bm = blockIdx.x * TS;
    const int bn = blockIdx.y * TS;
    const int tm = (tid >> 4) * 4;
    const int tn = (tid & 15) * 4;
    float acc[4][4] = {};

    for (int k0 = 0; k0 < K; k0 += BK) {
#pragma unroll
        for (int i = 0; i < 4; ++i) {
            int idx = tid + i * 256;
            int m = idx >> 4;
            int k = idx & 15;
            int row = bm + m, kk = k0 + k;
            float v = 0.f;
            if (row < M && kk < K) v = A[(size_t)row * K + kk];
            As[k][m] = v;
        }
#pragma unroll
        for (int i = 0; i < 4; ++i) {
            int idx = tid + i * 256;
            int k = idx >> 6;
            int n = idx & 63;
            int col = bn + n, kk = k0 + k;
            float v = 0.f;
            if (col < Ncol && kk < K) v = B[(size_t)kk * Ncol + col];
            Bs[k][n] = v;
        }
        __syncthreads();
#pragma unroll
        for (int k = 0; k < BK; ++k) {
            float4 av = *(const float4*)&As[k][tm];
            float4 bv = *(const float4*)&Bs[k][tn];
            float a4[4] = {av.x, av.y, av.z, av.w};
            float b4[4] = {bv.x, bv.y, bv.z, bv.w};
#pragma unroll
            for (int i = 0; i < 4; ++i)
#pragma unroll
                for (int j = 0; j < 4; ++j)
                    acc[i][j] = fmaf(a4[i], b4[j], acc[i][j]);
        }
        __syncthreads();
    }

#pragma unroll
    for (int i = 0; i < 4; ++i) {
        int row = bm + tm + i;
        if (row >= M) continue;
#pragma unroll
        for (int j = 0; j < 4; ++j) {
            int col = bn + tn + j;
            if (col < Ncol)
                C[(size_t)row * Ncol + col] = acc[i][j] + bias[col];
        }
    }
}

// ---------------------------------------------------------------------------
extern "C" void kernel_launch(void* const* d_in, const int* in_sizes, int n_in,
                              void* d_out, int out_size, void* d_ws, size_t ws_size,
                              hipStream_t stream)
{
    const float* node_feat = (const float*)d_in[0];
    const float* edge_feat = (const float*)d_in[1];
    const int*   src       = (const int*)d_in[2];
    const int*   dst       = (const int*)d_in[3];
    const int*   gid       = (const int*)d_in[4];
    const float* node_W = (const float*)d_in[6];
    const float* node_b = (const float*)d_in[7];
    const float* edge_W = (const float*)d_in[8];
    const float* edge_b = (const float*)d_in[9];
    const float* W1  = (const float*)d_in[10];
    const float* b1  = (const float*)d_in[11];
    const float* g1  = (const float*)d_in[12];
    const float* be1 = (const float*)d_in[13];
    const float* W2  = (const float*)d_in[14];
    const float* b2  = (const float*)d_in[15];
    const float* g2  = (const float*)d_in[16];
    const float* be2 = (const float*)d_in[17];
    const float* pred_W = (const float*)d_in[18];
    const float* pred_b = (const float*)d_in[19];
    float* out = (float*)d_out;

    // ---- workspace layout (bytes) ----
    char* base = (char*)d_ws;
    float* hn            = (float*)(base + 0);                 // 60,000,000
    float* x1            = (float*)(base + 60000000);          // 120,000,000
    unsigned short* nfH  = (unsigned short*)x1;                // alias (dead before x1 used)
    unsigned short* nfL  = nfH + (size_t)N_NODES * NFEAT;
    unsigned short* aggH = (unsigned short*)(base + 180000000);// 32,000,000
    unsigned short* aggL = aggH + (size_t)N_NODES * 320;       // 32,000,000
    float* h2            = (float*)(base + 180000000);         // alias agg planes
    unsigned short* wtH  = (unsigned short*)(base + 244000000);
    unsigned short* wtL  = (unsigned short*)(base + 244500000);
    int*   eids          = (int*)(base + 245000000);           // 3,200,000
    int*   P             = (int*)(base + 248200000);           // 200,004
    float* stats         = (float*)(base + 248400016);         // 4,800
    float* ab            = (float*)(base + 248404816);         // 4,800
    float* hg            = (float*)(base + 248409616);         // 307,200
    float* cnt           = (float*)(base + 248716816);         // 1,024

    dim3 blk(256);

    // ---- node encoder: hn = node_feat @ node_W + node_b (split-bf16 MFMA) ----
    split4<<<dim3((N_NODES * NFEAT / 4 + 255) / 256), blk, 0, stream>>>(
        node_feat, nfH, nfL, N_NODES * NFEAT / 4);
    conv_wt<<<dim3((384 * 128 + 255) / 256), blk, 0, stream>>>(
        node_W, wtH, wtL, NFEAT, DIM, 128, 384);
    gemm_pp<<<dim3(391, 3), blk, 0, stream>>>(
        nfH, nfL, wtH, wtL, node_b, hn, N_NODES, DIM, 128);

    // ---- CSR by dst (shared by all layers) ----
    hipMemsetAsync(P, 0, (N_NODES + 1) * sizeof(int), stream);
    csr_count<<<dim3((N_EDGES + 255) / 256), blk, 0, stream>>>(dst, P);
    csr_scan<<<dim3(1), dim3(1024), 0, stream>>>(P);
    csr_fill<<<dim3((N_EDGES + 255) / 256), blk, 0, stream>>>(dst, P, eids);

    for (int l = 0; l < N_LAYERS; ++l) {
        // agg planes = hn + sum relu(hn[src] + he), split bf16 [N][320]
        gather_agg<<<dim3(N_NODES / 4), blk, 0, stream>>>(
            hn, edge_feat, src, eids, P,
            edge_W + (size_t)l * EFEAT * DIM, edge_b + (size_t)l * DIM,
            aggH, aggL);

        // x1 = agg @ W1 + b1   [N, 600]
        conv_wt<<<dim3((640 * 320 + 255) / 256), blk, 0, stream>>>(
            W1 + (size_t)l * DIM * 2 * DIM, wtH, wtL, DIM, 2 * DIM, 320, 640);
        gemm_pp<<<dim3(391, 5), blk, 0, stream>>>(
            aggH, aggL, wtH, wtL, b1 + (size_t)l * 2 * DIM, x1,
            N_NODES, 2 * DIM, 320);

        // BN1 + relu (in place fp32)
        hipMemsetAsync(stats, 0, 4 * DIM * sizeof(float), stream);
        colstats<<<dim3((N_NODES + ROWS_PER_BLOCK - 1) / ROWS_PER_BLOCK), blk, 0, stream>>>(
            x1, stats, 2 * DIM);
        bn_finalize<<<dim3(3), blk, 0, stream>>>(
            stats, g1 + (size_t)l * 2 * DIM, be1 + (size_t)l * 2 * DIM, ab, 2 * DIM);
        bn_apply<<<dim3((N_NODES * 2 * DIM / 4 + 255) / 256), blk, 0, stream>>>(
            x1, ab, x1, N_NODES * 2 * DIM / 4, 2 * DIM, 1);

        // h2 = x1 @ W2 + b2  [N, 300] (A converted in-kernel)
        conv_wt<<<dim3((384 * 608 + 255) / 256), blk, 0, stream>>>(
            W2 + (size_t)l * 2 * DIM * DIM, wtH, wtL, 2 * DIM, DIM, 608, 384);
        gemm_af<<<dim3(391, 3), blk, 0, stream>>>(
            x1, wtH, wtL, b2 + (size_t)l * DIM, h2, N_NODES, DIM, 2 * DIM, 608);

        // BN2 (+relu except last) -> hn
        hipMemsetAsync(stats, 0, 2 * DIM * sizeof(float), stream);
        colstats<<<dim3((N_NODES + ROWS_PER_BLOCK - 1) / ROWS_PER_BLOCK), blk, 0, stream>>>(
            h2, stats, DIM);
        bn_finalize<<<dim3(2), blk, 0, stream>>>(
            stats, g2 + (size_t)l * DIM, be2 + (size_t)l * DIM, ab, DIM);
        bn_apply<<<dim3((N_NODES * DIM / 4 + 255) / 256), blk, 0, stream>>>(
            h2, ab, hn, N_NODES * DIM / 4, DIM, (l < N_LAYERS - 1) ? 1 : 0);
    }

    // ---- mean pool + head ----
    hipMemsetAsync(hg, 0, ((size_t)N_GRAPHS * DIM + N_GRAPHS) * sizeof(float), stream);
    pool_cnt<<<dim3((N_NODES + 255) / 256), blk, 0, stream>>>(gid, cnt);
    pool_scatter<<<dim3((N_NODES * DIM + 255) / 256), blk, 0, stream>>>(hn, gid, hg);
    pool_div<<<dim3((N_GRAPHS * DIM + 255) / 256), blk, 0, stream>>>(hg, cnt);

    sgemm_bias<<<dim3((N_GRAPHS + 63) / 64, (OUTD + 63) / 64), blk, 0, stream>>>(
        hg, pred_W, pred_b, out, N_GRAPHS, OUTD, DIM);
}